// Round 18
// baseline (52.883 us; speedup 1.0000x reference)
//
#include <hip/hip_runtime.h>

#define BB 32
#define NN 1024
#define MM 1024
#define DD 128

typedef __attribute__((ext_vector_type(4))) float f32x4;
typedef __attribute__((ext_vector_type(8))) __bf16 bf16x8;
typedef unsigned short ushort_t;
typedef unsigned int uint_t;

#define L2E 1.44269504f

__device__ __forceinline__ unsigned f2bf(float x) {
    unsigned u = __builtin_bit_cast(unsigned, x);
    return (u + 0x7fffu + ((u >> 16) & 1u)) >> 16;  // RNE bf16, finite inputs
}
__device__ __forceinline__ float bflo(uint_t u) {   // low bf16 -> f32
    return __builtin_bit_cast(float, u << 16);
}
__device__ __forceinline__ float bfhi(uint_t u) {   // high bf16 -> f32
    return __builtin_bit_cast(float, u & 0xffff0000u);
}

// async global->LDS, 16 B per lane; dest must be linear (base + lane*16)
#define GLOAD16(gp, lp)                                                     \
    __builtin_amdgcn_global_load_lds(                                       \
        (const __attribute__((address_space(1))) unsigned int*)(gp),        \
        (__attribute__((address_space(3))) unsigned int*)(lp), 16, 0, 0)

// ---- Kernel 1 (prep): gq = bf16(g)^T tiles ; e1 = h·a1 ;
//      BD[m] = pack(bf16(exp(e2)), bf16(exp(0.2*e2))) ------------------------
__global__ __launch_bounds__(256) void prep(
    const float* __restrict__ g, const float* __restrict__ h,
    const float* __restrict__ a1, const float* __restrict__ a2,
    ushort_t* __restrict__ gq, float* __restrict__ e1,
    uint_t* __restrict__ BD)
{
    __shared__ ushort_t tl[DD][66];  // +2 pad breaks write bank conflicts
    int b = blockIdx.y, m0 = blockIdx.x * 64, t = threadIdx.x;

    #pragma unroll
    for (int i = 0; i < 8; i++) {
        int idx = i * 256 + t;
        int m = idx >> 5;            // 32 consecutive lanes share row m
        int c4 = (idx & 31) * 4;
        float4 v = *(const float4*)(h + ((size_t)(b * NN + m0 + m)) * DD + c4);
        float4 av = *(const float4*)(a1 + c4);
        float p = v.x * av.x + v.y * av.y + v.z * av.z + v.w * av.w;
        #pragma unroll
        for (int s = 16; s; s >>= 1) p += __shfl_xor(p, s);
        if ((t & 31) == 0) e1[b * NN + m0 + m] = p;
    }
    #pragma unroll
    for (int i = 0; i < 8; i++) {
        int idx = i * 256 + t;
        int m = idx >> 5;
        int c4 = (idx & 31) * 4;
        float4 v = *(const float4*)(g + ((size_t)(b * MM + m0 + m)) * DD + c4);
        tl[c4 + 0][m] = (ushort_t)f2bf(v.x);
        tl[c4 + 1][m] = (ushort_t)f2bf(v.y);
        tl[c4 + 2][m] = (ushort_t)f2bf(v.z);
        tl[c4 + 3][m] = (ushort_t)f2bf(v.w);
        float4 av = *(const float4*)(a2 + c4);
        float p = v.x * av.x + v.y * av.y + v.z * av.z + v.w * av.w;
        #pragma unroll
        for (int s = 16; s; s >>= 1) p += __shfl_xor(p, s);
        if ((t & 31) == 0) {
            uint_t pb = f2bf(__builtin_amdgcn_exp2f(L2E * p));
            uint_t pd = f2bf(__builtin_amdgcn_exp2f(0.2f * L2E * p));
            BD[b * MM + m0 + m] = pb | (pd << 16);
        }
    }
    __syncthreads();
    #pragma unroll
    for (int i = 0; i < 4; i++) {
        int idx = i * 256 + t;
        int d = idx >> 3;            // 0..127
        int c = (idx & 7) * 8;       // local m group
        int4 o;
        o.x = (int)((unsigned)tl[d][c + 0] | ((unsigned)tl[d][c + 1] << 16));
        o.y = (int)((unsigned)tl[d][c + 2] | ((unsigned)tl[d][c + 3] << 16));
        o.z = (int)((unsigned)tl[d][c + 4] | ((unsigned)tl[d][c + 5] << 16));
        o.w = (int)((unsigned)tl[d][c + 6] | ((unsigned)tl[d][c + 7] << 16));
        int mg = m0 + c;
        *(int4*)(gq + (((size_t)((b * 32 + (mg >> 5)) * DD + d)) << 5) + (mg & 31)) = o;
    }
}

// ---- Kernel 2: fused adj+softmax+PV, ring-4 LDS, 2x2 wave tiling ------------
// block = 64 rows x 128 d; wave (wr, wd) = 32 rows x 64 d (2 A-frags, 4 B-frags).
// Balanced tiling cuts per-wave LDS reads 14->10 KB/chunk; BD packed bf16.
__global__ __launch_bounds__(256, 2) void attn_tiled(
    const int* __restrict__ adj, const ushort_t* __restrict__ gq,
    const float* __restrict__ e1, const uint_t* __restrict__ BD,
    float* __restrict__ out)
{
    __shared__ __align__(16) uint_t BDS[MM];            // 4 KB
    __shared__ __align__(16) int adjS[4][64 * 32];      // 4 x 8 KB
    __shared__ __align__(16) ushort_t gqS[4][128 * 32]; // 4 x 8 KB

    int b = blockIdx.y, n0 = blockIdx.x * 64, t = threadIdx.x;
    int wid = t >> 6, lane = t & 63;
    int wr = wid >> 1, wd = wid & 1;
    int rlo = lane & 15, hh = lane >> 4;

    // stage BD table
    *(uint4*)(&BDS[t * 4]) = *(const uint4*)(BD + b * MM + t * 4);
    float An[2], Cn[2], invA[2];
    #pragma unroll
    for (int f = 0; f < 2; f++) {
        float e1r = e1[b * NN + n0 + wr * 32 + f * 16 + rlo];
        An[f]   = __builtin_amdgcn_exp2f(L2E * e1r);
        Cn[f]   = __builtin_amdgcn_exp2f(0.2f * L2E * e1r);
        invA[f] = __builtin_amdgcn_exp2f(-L2E * e1r);
    }
    __syncthreads();                 // table ready (no DMA in flight yet)

    const int* adjb = adj + (size_t)(b * NN + n0) * MM;
    const ushort_t* gqb = gq + (size_t)b * (32 * DD * 32);

    // adj staging: di in {t, t+256} covers 512 x 16B slots (64 rows x 8 slots),
    // source-swizzled seg = slot ^ (row&7)
    int adi0 = t, adi1 = t + 256;
    int arow0 = adi0 >> 3, aseg0 = (adi0 & 7) ^ (arow0 & 7);
    int arow1 = adi1 >> 3, aseg1 = (adi1 & 7) ^ (arow1 & 7);
    // gq staging: 512 slots = 128 d-rows x 4 slots of 8 shorts,
    // source-swizzled seg = slot ^ ((d>>1)&3)
    int gd0 = adi0 >> 2, gseg0 = (adi0 & 3) ^ ((gd0 >> 1) & 3);
    int gd1 = adi1 >> 2, gseg1 = (adi1 & 3) ^ ((gd1 >> 1) & 3);

#define STAGE(P, K) do {                                                    \
        GLOAD16(adjb + (size_t)arow0 * MM + (K) * 32 + aseg0 * 4,           \
                &adjS[P][adi0 * 4]);                                        \
        GLOAD16(adjb + (size_t)arow1 * MM + (K) * 32 + aseg1 * 4,           \
                &adjS[P][adi1 * 4]);                                        \
        GLOAD16(gqb + (size_t)(K) * 4096 + gd0 * 32 + gseg0 * 8,            \
                &gqS[P][adi0 * 8]);                                         \
        GLOAD16(gqb + (size_t)(K) * 4096 + gd1 * 32 + gseg1 * 8,            \
                &gqS[P][adi1 * 8]);                                         \
    } while (0)

    f32x4 acc[2][4];
    #pragma unroll
    for (int f = 0; f < 2; f++)
        #pragma unroll
        for (int j = 0; j < 4; j++) acc[f][j] = (f32x4){0.f, 0.f, 0.f, 0.f};
    float zl[2] = {0.f, 0.f};
    int dcnt[2] = {0, 0};

#define COMPUTE(P, K) do {                                                  \
        uint4 bd0 = *(const uint4*)(&BDS[(K) * 32 + 8 * hh]);               \
        uint4 bd1 = *(const uint4*)(&BDS[(K) * 32 + 8 * hh + 4]);           \
        uint_t bdv[8] = {bd0.x, bd0.y, bd0.z, bd0.w,                        \
                         bd1.x, bd1.y, bd1.z, bd1.w};                       \
        int4 cb[4];                                                         \
        _Pragma("unroll")                                                   \
        for (int j = 0; j < 4; j++) {                                       \
            int d = wd * 64 + j * 16 + rlo;                                 \
            cb[j] = *(const int4*)(                                         \
                &gqS[P][d * 32 + (hh ^ ((rlo >> 1) & 3)) * 8]);             \
        }                                                                   \
        _Pragma("unroll")                                                   \
        for (int f = 0; f < 2; f++) {                                       \
            int r = wr * 32 + f * 16 + rlo;                                 \
            int r8 = r & 7;                                                 \
            int4 a0 = *(const int4*)(                                       \
                &adjS[P][r * 32 + ((2 * hh) ^ r8) * 4]);                    \
            int4 a1 = *(const int4*)(                                       \
                &adjS[P][r * 32 + ((2 * hh + 1) ^ r8) * 4]);                \
            int ax[8] = {a0.x, a0.y, a0.z, a0.w, a1.x, a1.y, a1.z, a1.w};   \
            bf16x8 af;                                                      \
            _Pragma("unroll")                                               \
            for (int jj = 0; jj < 8; jj++) {                                \
                float Bv = bflo(bdv[jj]);                                   \
                float Dv = bfhi(bdv[jj]);                                   \
                float val = (Bv > invA[f]) ? Bv * An[f] : Dv * Cn[f];       \
                float wv = (ax[jj] > 0) ? val : 0.f;                        \
                zl[f] += wv;                                                \
                dcnt[f] += ax[jj];                                          \
                af[jj] = (__bf16)wv;                                        \
            }                                                               \
            _Pragma("unroll")                                               \
            for (int j = 0; j < 4; j++)                                     \
                acc[f][j] = __builtin_amdgcn_mfma_f32_16x16x32_bf16(        \
                    af, __builtin_bit_cast(bf16x8, cb[j]), acc[f][j], 0,0,0);\
        }                                                                   \
    } while (0)

    // prologue: 3 stages in flight (12 DMA ops/thread)
    STAGE(0, 0); STAGE(1, 1); STAGE(2, 2);

    for (int k = 0; k < 30; ++k) {
        asm volatile("s_waitcnt vmcnt(8)" ::: "memory");  // stage k landed
        __builtin_amdgcn_s_barrier();                     // raw: no drain
        __builtin_amdgcn_sched_barrier(0);
        if (k < 29) STAGE((k + 3) & 3, k + 3);            // overwrites (k-1)&3
        COMPUTE(k & 3, k);
    }
    asm volatile("s_waitcnt vmcnt(4)" ::: "memory");      // stage 30 landed
    __builtin_amdgcn_s_barrier();
    __builtin_amdgcn_sched_barrier(0);
    COMPUTE(2, 30);
    asm volatile("s_waitcnt vmcnt(0)" ::: "memory");      // stage 31 landed
    __builtin_amdgcn_s_barrier();
    __builtin_amdgcn_sched_barrier(0);
    COMPUTE(3, 31);

#undef COMPUTE
#undef STAGE

    // per-row Z, deg: lanes sharing rlo hold partials -> reduce lane bits 4,5
    #pragma unroll
    for (int f = 0; f < 2; f++) {
        zl[f] += __shfl_xor(zl[f], 16); zl[f] += __shfl_xor(zl[f], 32);
        dcnt[f] += __shfl_xor(dcnt[f], 16); dcnt[f] += __shfl_xor(dcnt[f], 32);
    }

    // C layout: col = rlo, row(within frag) = 4*hh + rg
    float* ob = out + ((size_t)(b * NN + n0 + wr * 32)) * DD + wd * 64 + rlo;
    #pragma unroll
    for (int f = 0; f < 2; f++) {
        float sc = (dcnt[f] > 0) ? ((float)dcnt[f] / zl[f]) : 0.f;
        #pragma unroll
        for (int rg = 0; rg < 4; rg++) {
            float scv = __shfl(sc, 4 * hh + rg);
            #pragma unroll
            for (int j = 0; j < 4; j++)
                ob[(size_t)(f * 16 + 4 * hh + rg) * DD + j * 16] =
                    acc[f][j][rg] * scv;
        }
    }
}

extern "C" void kernel_launch(void* const* d_in, const int* in_sizes, int n_in,
                              void* d_out, int out_size, void* d_ws, size_t ws_size,
                              hipStream_t stream) {
    const float* h   = (const float*)d_in[0];
    const float* g   = (const float*)d_in[1];
    const int*   adj = (const int*)d_in[2];
    const float* a1  = (const float*)d_in[3];
    const float* a2  = (const float*)d_in[4];
    float* out = (float*)d_out;

    // workspace: e1 @0 (128 KB), BD @128K (128 KB), gq @512K (8 MB)
    char* ws = (char*)d_ws;
    float*    e1 = (float*)(ws);
    uint_t*   BD = (uint_t*)(ws + (128u << 10));
    ushort_t* gq = (ushort_t*)(ws + (512u << 10));

    prep<<<dim3(MM / 64, BB), 256, 0, stream>>>(g, h, a1, a2, gq, e1, BD);
    attn_tiled<<<dim3(NN / 64, BB), 256, 0, stream>>>(adj, gq, e1, BD, out);
}

// Round 21
// 50.277 us; speedup vs baseline: 1.0518x; 1.0518x over previous
//
#include <hip/hip_runtime.h>

#define BB 32
#define NN 1024
#define MM 1024
#define DD 128

typedef __attribute__((ext_vector_type(4))) float f32x4;
typedef __attribute__((ext_vector_type(8))) __bf16 bf16x8;
typedef unsigned short ushort_t;
typedef unsigned int uint_t;

#define L2E 1.44269504f

__device__ __forceinline__ unsigned f2bf(float x) {
    unsigned u = __builtin_bit_cast(unsigned, x);
    return (u + 0x7fffu + ((u >> 16) & 1u)) >> 16;  // RNE bf16, finite inputs
}

// async global->LDS, 16 B per lane; dest must be linear (base + lane*16)
#define GLOAD16(gp, lp)                                                     \
    __builtin_amdgcn_global_load_lds(                                       \
        (const __attribute__((address_space(1))) unsigned int*)(gp),        \
        (__attribute__((address_space(3))) unsigned int*)(lp), 16, 0, 0)

// ---- Kernel 1 (prep): gq = bf16(g)^T tiles ; e1 = h·a1 ;
//      e2B = exp(e2), e2D = exp(0.2*e2)  (factorized-softmax tables) ---------
__global__ __launch_bounds__(256) void prep(
    const float* __restrict__ g, const float* __restrict__ h,
    const float* __restrict__ a1, const float* __restrict__ a2,
    ushort_t* __restrict__ gq, float* __restrict__ e1,
    float* __restrict__ e2B, float* __restrict__ e2D)
{
    __shared__ ushort_t tl[DD][66];  // +2 pad breaks write bank conflicts
    int b = blockIdx.y, m0 = blockIdx.x * 64, t = threadIdx.x;

    #pragma unroll
    for (int i = 0; i < 8; i++) {
        int idx = i * 256 + t;
        int m = idx >> 5;            // 32 consecutive lanes share row m
        int c4 = (idx & 31) * 4;
        float4 v = *(const float4*)(h + ((size_t)(b * NN + m0 + m)) * DD + c4);
        float4 av = *(const float4*)(a1 + c4);
        float p = v.x * av.x + v.y * av.y + v.z * av.z + v.w * av.w;
        #pragma unroll
        for (int s = 16; s; s >>= 1) p += __shfl_xor(p, s);
        if ((t & 31) == 0) e1[b * NN + m0 + m] = p;
    }
    #pragma unroll
    for (int i = 0; i < 8; i++) {
        int idx = i * 256 + t;
        int m = idx >> 5;
        int c4 = (idx & 31) * 4;
        float4 v = *(const float4*)(g + ((size_t)(b * MM + m0 + m)) * DD + c4);
        tl[c4 + 0][m] = (ushort_t)f2bf(v.x);
        tl[c4 + 1][m] = (ushort_t)f2bf(v.y);
        tl[c4 + 2][m] = (ushort_t)f2bf(v.z);
        tl[c4 + 3][m] = (ushort_t)f2bf(v.w);
        float4 av = *(const float4*)(a2 + c4);
        float p = v.x * av.x + v.y * av.y + v.z * av.z + v.w * av.w;
        #pragma unroll
        for (int s = 16; s; s >>= 1) p += __shfl_xor(p, s);
        if ((t & 31) == 0) {
            e2B[b * MM + m0 + m] = __builtin_amdgcn_exp2f(L2E * p);
            e2D[b * MM + m0 + m] = __builtin_amdgcn_exp2f(0.2f * L2E * p);
        }
    }
    __syncthreads();
    #pragma unroll
    for (int i = 0; i < 4; i++) {
        int idx = i * 256 + t;
        int d = idx >> 3;            // 0..127
        int c = (idx & 7) * 8;       // local m group
        int4 o;
        o.x = (int)((unsigned)tl[d][c + 0] | ((unsigned)tl[d][c + 1] << 16));
        o.y = (int)((unsigned)tl[d][c + 2] | ((unsigned)tl[d][c + 3] << 16));
        o.z = (int)((unsigned)tl[d][c + 4] | ((unsigned)tl[d][c + 5] << 16));
        o.w = (int)((unsigned)tl[d][c + 6] | ((unsigned)tl[d][c + 7] << 16));
        int mg = m0 + c;
        *(int4*)(gq + (((size_t)((b * 32 + (mg >> 5)) * DD + d)) << 5) + (mg & 31)) = o;
    }
}

// ---- Kernel 2: fused adj+softmax+PV, 64-m chunks, LDS double-buffer ---------
// block = 4 waves x 16 rows = 64 rows, all 128 d. Chunk = 64 m: adj reads are
// 256 B CONTIGUOUS per row per stage (vs 128 B at 32-m) -> better DRAM row
// locality. 16 iterations: [vmcnt(0) -> raw s_barrier -> STAGE(k+1) ->
// compute 2 ksteps]. LDS 72 KB -> 2 blocks/CU.
__global__ __launch_bounds__(256, 2) void attn_tiled(
    const int* __restrict__ adj, const ushort_t* __restrict__ gq,
    const float* __restrict__ e1, const float* __restrict__ e2B,
    const float* __restrict__ e2D, float* __restrict__ out)
{
    __shared__ __align__(16) float BfS[MM];              // 4 KB
    __shared__ __align__(16) float DfS[MM];              // 4 KB
    __shared__ __align__(16) int adjS[2][64 * 64];       // 2 x 16 KB
    __shared__ __align__(16) ushort_t gqS[2][2 * 128 * 32]; // 2 x 16 KB

    int b = blockIdx.y, n0 = blockIdx.x * 64, t = threadIdx.x;
    int wid = t >> 6, lane = t & 63;
    int rlo = lane & 15, hh = lane >> 4;
    int r = wid * 16 + rlo;          // block-local row 0..63

    // stage B/D tables
    *(float4*)(&BfS[t * 4]) = *(const float4*)(e2B + b * MM + t * 4);
    *(float4*)(&DfS[t * 4]) = *(const float4*)(e2D + b * MM + t * 4);
    float e1r = e1[b * NN + n0 + r];
    float An   = __builtin_amdgcn_exp2f(L2E * e1r);
    float Cn   = __builtin_amdgcn_exp2f(0.2f * L2E * e1r);
    float invA = __builtin_amdgcn_exp2f(-L2E * e1r);
    __syncthreads();                 // tables ready (no DMA in flight yet)

    const int* adjb = adj + (size_t)(b * NN + n0) * MM;
    const ushort_t* gqb = gq + (size_t)b * (32 * DD * 32);

    // adj staging: 1024 x 16B slots = 64 rows x 16 slots; src-swizzled
    // seg = slot ^ (row&15). Per row: 256 B contiguous (64 words).
    int adi[4], aoff[4];
    #pragma unroll
    for (int i = 0; i < 4; i++) {
        adi[i] = t + i * 256;
        int arow = adi[i] >> 4, aseg = (adi[i] & 15) ^ (arow & 15);
        aoff[i] = arow * MM + aseg * 4;
    }
    // gq staging: 1024 slots = 2 m-tiles x (128 d x 4 slots of 8 shorts),
    // src-swizzled seg = slot ^ ((d>>1)&3)
    int gtile[4], goff[4];
    #pragma unroll
    for (int i = 0; i < 4; i++) {
        int di = t + i * 256;
        gtile[i] = di >> 9;
        int idx = di & 511;
        int gd = idx >> 2, gseg = (idx & 3) ^ ((gd >> 1) & 3);
        goff[i] = gd * 32 + gseg * 8;
    }

#define STAGE(P, K) do {                                                    \
        _Pragma("unroll")                                                   \
        for (int i = 0; i < 4; i++)                                         \
            GLOAD16(adjb + (size_t)aoff[i] + (K) * 64,                      \
                    &adjS[P][adi[i] * 4]);                                  \
        _Pragma("unroll")                                                   \
        for (int i = 0; i < 4; i++)                                         \
            GLOAD16(gqb + (size_t)(2 * (K) + gtile[i]) * 4096 + goff[i],    \
                    &gqS[P][(t + i * 256) * 8]);                            \
    } while (0)

    f32x4 acc[8];
    #pragma unroll
    for (int j = 0; j < 8; j++) acc[j] = (f32x4){0.f, 0.f, 0.f, 0.f};
    float zl = 0.f;
    int dcnt = 0;

#define KSTEP(P, K, KS) do {                                                \
        int4 a0 = *(const int4*)(                                           \
            &adjS[P][r * 64 + (((KS) * 8 + 2 * hh) ^ rlo) * 4]);            \
        int4 a1 = *(const int4*)(                                           \
            &adjS[P][r * 64 + (((KS) * 8 + 2 * hh + 1) ^ rlo) * 4]);        \
        int mo = (K) * 64 + (KS) * 32 + 8 * hh;                             \
        float4 b0 = *(const float4*)(&BfS[mo]);                             \
        float4 b1 = *(const float4*)(&BfS[mo + 4]);                         \
        float4 d0 = *(const float4*)(&DfS[mo]);                             \
        float4 d1 = *(const float4*)(&DfS[mo + 4]);                         \
        float Bv[8] = {b0.x, b0.y, b0.z, b0.w, b1.x, b1.y, b1.z, b1.w};     \
        float Dv[8] = {d0.x, d0.y, d0.z, d0.w, d1.x, d1.y, d1.z, d1.w};     \
        int   ax[8] = {a0.x, a0.y, a0.z, a0.w, a1.x, a1.y, a1.z, a1.w};     \
        bf16x8 af;                                                          \
        _Pragma("unroll")                                                   \
        for (int jj = 0; jj < 8; jj++) {                                    \
            float val = (Bv[jj] > invA) ? Bv[jj] * An : Dv[jj] * Cn;        \
            float wv = (ax[jj] > 0) ? val : 0.f;                            \
            zl += wv;                                                       \
            dcnt += ax[jj];                                                 \
            af[jj] = (__bf16)wv;                                            \
        }                                                                   \
        _Pragma("unroll")                                                   \
        for (int j = 0; j < 8; j++) {                                       \
            int d = j * 16 + rlo;                                           \
            int4 bv = *(const int4*)(&gqS[P][(KS) * 4096 + d * 32 +         \
                                             (hh ^ ((rlo >> 1) & 3)) * 8]); \
            acc[j] = __builtin_amdgcn_mfma_f32_16x16x32_bf16(               \
                         af, __builtin_bit_cast(bf16x8, bv), acc[j], 0,0,0);\
        }                                                                   \
    } while (0)

    STAGE(0, 0);

    for (int k = 0; k < 16; ++k) {
        asm volatile("s_waitcnt vmcnt(0)" ::: "memory");  // stage k landed
        __builtin_amdgcn_s_barrier();                     // raw: no drain
        __builtin_amdgcn_sched_barrier(0);
        if (k < 15) STAGE((k + 1) & 1, k + 1);
        KSTEP(k & 1, k, 0);
        KSTEP(k & 1, k, 1);
    }

#undef KSTEP
#undef STAGE

    // per-row Z, deg: lanes sharing rlo hold partials -> reduce lane bits 4,5
    zl += __shfl_xor(zl, 16); zl += __shfl_xor(zl, 32);
    dcnt += __shfl_xor(dcnt, 16); dcnt += __shfl_xor(dcnt, 32);
    float sc = (dcnt > 0) ? ((float)dcnt / zl) : 0.f;    // = deg / Z

    float scr[4];
    #pragma unroll
    for (int rg = 0; rg < 4; rg++) scr[rg] = __shfl(sc, 4 * hh + rg);

    // C layout: col = rlo, row(within frag) = 4*hh + rg
    float* ob = out + ((size_t)(b * NN + n0 + wid * 16)) * DD + rlo;
    #pragma unroll
    for (int j = 0; j < 8; j++)
        #pragma unroll
        for (int rg = 0; rg < 4; rg++)
            ob[(size_t)(4 * hh + rg) * DD + j * 16] = acc[j][rg] * scr[rg];
}

extern "C" void kernel_launch(void* const* d_in, const int* in_sizes, int n_in,
                              void* d_out, int out_size, void* d_ws, size_t ws_size,
                              hipStream_t stream) {
    const float* h   = (const float*)d_in[0];
    const float* g   = (const float*)d_in[1];
    const int*   adj = (const int*)d_in[2];
    const float* a1  = (const float*)d_in[3];
    const float* a2  = (const float*)d_in[4];
    float* out = (float*)d_out;

    // workspace: e1 @0 (128 KB), e2B @128K (128 KB), e2D @256K (128 KB),
    //            gq @512K (8 MB)
    char* ws = (char*)d_ws;
    float*    e1  = (float*)(ws);
    float*    e2B = (float*)(ws + (128u << 10));
    float*    e2D = (float*)(ws + (256u << 10));
    ushort_t* gq  = (ushort_t*)(ws + (512u << 10));

    prep<<<dim3(MM / 64, BB), 256, 0, stream>>>(g, h, a1, a2, gq, e1, e2B, e2D);
    attn_tiled<<<dim3(NN / 64, BB), 256, 0, stream>>>(adj, gq, e1, e2B, e2D, out);
}

// Round 22
// 47.854 us; speedup vs baseline: 1.1051x; 1.0506x over previous
//
#include <hip/hip_runtime.h>

#define BB 32
#define NN 1024
#define MM 1024
#define DD 128

typedef __attribute__((ext_vector_type(4))) float f32x4;
typedef __attribute__((ext_vector_type(8))) __bf16 bf16x8;
typedef unsigned short ushort_t;
typedef unsigned int uint_t;

#define L2E 1.44269504f

__device__ __forceinline__ unsigned f2bf(float x) {
    unsigned u = __builtin_bit_cast(unsigned, x);
    return (u + 0x7fffu + ((u >> 16) & 1u)) >> 16;  // RNE bf16, finite inputs
}

// async global->LDS, 16 B per lane; dest must be linear (base + lane*16)
#define GLOAD16(gp, lp)                                                     \
    __builtin_amdgcn_global_load_lds(                                       \
        (const __attribute__((address_space(1))) unsigned int*)(gp),        \
        (__attribute__((address_space(3))) unsigned int*)(lp), 16, 0, 0)

// ---- Kernel 1 (prep): gq = bf16(g)^T tiles ; e1 = h·a1 ;
//      e2B = exp(e2), e2D = exp(0.2*e2)  (factorized-softmax tables) ---------
__global__ __launch_bounds__(256) void prep(
    const float* __restrict__ g, const float* __restrict__ h,
    const float* __restrict__ a1, const float* __restrict__ a2,
    ushort_t* __restrict__ gq, float* __restrict__ e1,
    float* __restrict__ e2B, float* __restrict__ e2D)
{
    __shared__ ushort_t tl[DD][66];  // +2 pad breaks write bank conflicts
    int b = blockIdx.y, m0 = blockIdx.x * 64, t = threadIdx.x;

    #pragma unroll
    for (int i = 0; i < 8; i++) {
        int idx = i * 256 + t;
        int m = idx >> 5;            // 32 consecutive lanes share row m
        int c4 = (idx & 31) * 4;
        float4 v = *(const float4*)(h + ((size_t)(b * NN + m0 + m)) * DD + c4);
        float4 av = *(const float4*)(a1 + c4);
        float p = v.x * av.x + v.y * av.y + v.z * av.z + v.w * av.w;
        #pragma unroll
        for (int s = 16; s; s >>= 1) p += __shfl_xor(p, s);
        if ((t & 31) == 0) e1[b * NN + m0 + m] = p;
    }
    #pragma unroll
    for (int i = 0; i < 8; i++) {
        int idx = i * 256 + t;
        int m = idx >> 5;
        int c4 = (idx & 31) * 4;
        float4 v = *(const float4*)(g + ((size_t)(b * MM + m0 + m)) * DD + c4);
        tl[c4 + 0][m] = (ushort_t)f2bf(v.x);
        tl[c4 + 1][m] = (ushort_t)f2bf(v.y);
        tl[c4 + 2][m] = (ushort_t)f2bf(v.z);
        tl[c4 + 3][m] = (ushort_t)f2bf(v.w);
        float4 av = *(const float4*)(a2 + c4);
        float p = v.x * av.x + v.y * av.y + v.z * av.z + v.w * av.w;
        #pragma unroll
        for (int s = 16; s; s >>= 1) p += __shfl_xor(p, s);
        if ((t & 31) == 0) {
            e2B[b * MM + m0 + m] = __builtin_amdgcn_exp2f(L2E * p);
            e2D[b * MM + m0 + m] = __builtin_amdgcn_exp2f(0.2f * L2E * p);
        }
    }
    __syncthreads();
    #pragma unroll
    for (int i = 0; i < 4; i++) {
        int idx = i * 256 + t;
        int d = idx >> 3;            // 0..127
        int c = (idx & 7) * 8;       // local m group
        int4 o;
        o.x = (int)((unsigned)tl[d][c + 0] | ((unsigned)tl[d][c + 1] << 16));
        o.y = (int)((unsigned)tl[d][c + 2] | ((unsigned)tl[d][c + 3] << 16));
        o.z = (int)((unsigned)tl[d][c + 4] | ((unsigned)tl[d][c + 5] << 16));
        o.w = (int)((unsigned)tl[d][c + 6] | ((unsigned)tl[d][c + 7] << 16));
        int mg = m0 + c;
        *(int4*)(gq + (((size_t)((b * 32 + (mg >> 5)) * DD + d)) << 5) + (mg & 31)) = o;
    }
}

// ---- Kernel 2: fused adj+softmax+PV, m-split 8-wave block -------------------
// 512 thr = 2 wave-groups x 4 waves. Group 0: m-chunks 0-15; group 1: 16-31.
// Each group: 64 rows x 128 d, own ring-2 LDS pipeline (T3 2-phase).
// 512 blocks x 8 waves = 16 waves/CU (2 blocks/CU, LDS 72 KB). Same staged
// bytes as r13, HALF the iterations, DOUBLE the occupancy, zero redundancy.
// Epilogue: group 1 dumps acc/Z/deg to LDS scratch; group 0 sums + stores.
__global__ __launch_bounds__(512, 4) void attn_tiled(
    const int* __restrict__ adj, const ushort_t* __restrict__ gq,
    const float* __restrict__ e1, const float* __restrict__ e2B,
    const float* __restrict__ e2D, float* __restrict__ out)
{
    __shared__ __align__(16) float BfS[MM];                // 4 KB
    __shared__ __align__(16) float DfS[MM];                // 4 KB
    __shared__ __align__(16) int adjS[2][2][64 * 32];      // 32 KB [grp][buf]
    __shared__ __align__(16) ushort_t gqS[2][2][128 * 32]; // 32 KB [grp][buf]

    int b = blockIdx.y, n0 = blockIdx.x * 64, t = threadIdx.x;
    int half = t >> 8;               // wave-group 0/1
    int tt = t & 255;                // index within group
    int wid4 = tt >> 6, lane = t & 63;
    int rlo = lane & 15, hh = lane >> 4;
    int r = wid4 * 16 + rlo;         // block-local row 0..63 (same both groups)
    int c0 = half * 16;              // group's first m-chunk

    // stage tables (group 0 -> BfS, group 1 -> DfS)
    if (half == 0)
        *(float4*)(&BfS[tt * 4]) = *(const float4*)(e2B + b * MM + tt * 4);
    else
        *(float4*)(&DfS[tt * 4]) = *(const float4*)(e2D + b * MM + tt * 4);
    float e1r = e1[b * NN + n0 + r];
    float An   = __builtin_amdgcn_exp2f(L2E * e1r);
    float Cn   = __builtin_amdgcn_exp2f(0.2f * L2E * e1r);
    float invA = __builtin_amdgcn_exp2f(-L2E * e1r);

    const int* adjb = adj + (size_t)(b * NN + n0) * MM;
    const ushort_t* gqb = gq + (size_t)b * (32 * DD * 32);

    // staging indices within group (tt covers 512 16B slots via tt, tt+256)
    int adi0 = tt, adi1 = tt + 256;
    int arow0 = adi0 >> 3, aseg0 = (adi0 & 7) ^ (arow0 & 7);
    int arow1 = adi1 >> 3, aseg1 = (adi1 & 7) ^ (arow1 & 7);
    int gd0 = adi0 >> 2, gseg0 = (adi0 & 3) ^ ((gd0 >> 1) & 3);
    int gd1 = adi1 >> 2, gseg1 = (adi1 & 3) ^ ((gd1 >> 1) & 3);

#define STAGE(P, C) do {                                                    \
        GLOAD16(adjb + (size_t)arow0 * MM + (C) * 32 + aseg0 * 4,           \
                &adjS[half][P][adi0 * 4]);                                  \
        GLOAD16(adjb + (size_t)arow1 * MM + (C) * 32 + aseg1 * 4,           \
                &adjS[half][P][adi1 * 4]);                                  \
        GLOAD16(gqb + (size_t)(C) * 4096 + gd0 * 32 + gseg0 * 8,            \
                &gqS[half][P][adi0 * 8]);                                   \
        GLOAD16(gqb + (size_t)(C) * 4096 + gd1 * 32 + gseg1 * 8,            \
                &gqS[half][P][adi1 * 8]);                                   \
    } while (0)

    f32x4 acc[8];
    #pragma unroll
    for (int j = 0; j < 8; j++) acc[j] = (f32x4){0.f, 0.f, 0.f, 0.f};
    float zl = 0.f;
    int dcnt = 0;
    int r8 = r & 7;

#define COMPUTE(P, C) do {                                                  \
        int4 a0 = *(const int4*)(&adjS[half][P][r * 32 + ((2*hh) ^ r8)*4]); \
        int4 av1 = *(const int4*)(                                          \
            &adjS[half][P][r * 32 + ((2*hh + 1) ^ r8) * 4]);                \
        int mo = (C) * 32 + 8 * hh;                                         \
        float4 b0 = *(const float4*)(&BfS[mo]);                             \
        float4 b1 = *(const float4*)(&BfS[mo + 4]);                         \
        float4 d0 = *(const float4*)(&DfS[mo]);                             \
        float4 d1 = *(const float4*)(&DfS[mo + 4]);                         \
        float Bv[8] = {b0.x, b0.y, b0.z, b0.w, b1.x, b1.y, b1.z, b1.w};     \
        float Dv[8] = {d0.x, d0.y, d0.z, d0.w, d1.x, d1.y, d1.z, d1.w};     \
        int   ax[8] = {a0.x, a0.y, a0.z, a0.w,                              \
                       av1.x, av1.y, av1.z, av1.w};                         \
        bf16x8 af;                                                          \
        _Pragma("unroll")                                                   \
        for (int jj = 0; jj < 8; jj++) {                                    \
            float val = (Bv[jj] > invA) ? Bv[jj] * An : Dv[jj] * Cn;        \
            float wv = (ax[jj] > 0) ? val : 0.f;                            \
            zl += wv;                                                       \
            dcnt += ax[jj];                                                 \
            af[jj] = (__bf16)wv;                                            \
        }                                                                   \
        _Pragma("unroll")                                                   \
        for (int j = 0; j < 8; j++) {                                       \
            int d = j * 16 + rlo;                                           \
            int4 bv = *(const int4*)(&gqS[half][P][d * 32 +                 \
                                     (hh ^ ((rlo >> 1) & 3)) * 8]);         \
            acc[j] = __builtin_amdgcn_mfma_f32_16x16x32_bf16(               \
                         af, __builtin_bit_cast(bf16x8, bv), acc[j], 0,0,0);\
        }                                                                   \
    } while (0)

    // prologue: stage chunk c0; drain DMA + table ds_writes; barrier
    STAGE(0, c0);
    asm volatile("s_waitcnt vmcnt(0) lgkmcnt(0)" ::: "memory");
    __builtin_amdgcn_s_barrier();

    // T3 2-phase: issue next stage, compute current, drain, barrier
    for (int k = 0; k < 16; ++k) {
        if (k < 15) STAGE((k + 1) & 1, c0 + k + 1);
        COMPUTE(k & 1, c0 + k);
        asm volatile("s_waitcnt vmcnt(0)" ::: "memory");
        __builtin_amdgcn_s_barrier();
    }

#undef COMPUTE
#undef STAGE

    // ---- combine the two m-halves (pair: thread tt of group 1 -> group 0) ---
    f32x4* accS = (f32x4*)&adjS[0][0][0];   // 2048 f32x4 = 32 KB scratch
    if (half == 1) {
        #pragma unroll
        for (int j = 0; j < 8; j++) accS[j * 256 + tt] = acc[j];  // conflict-free
        BfS[tt] = zl;
        DfS[tt] = (float)dcnt;
    }
    __syncthreads();
    if (half == 0) {
        #pragma unroll
        for (int j = 0; j < 8; j++) acc[j] += accS[j * 256 + tt];
        zl += BfS[tt];
        dcnt += (int)DfS[tt];

        // per-row Z, deg: lanes sharing rlo -> reduce over lane bits 4,5
        zl += __shfl_xor(zl, 16); zl += __shfl_xor(zl, 32);
        dcnt += __shfl_xor(dcnt, 16); dcnt += __shfl_xor(dcnt, 32);
        float sc = (dcnt > 0) ? ((float)dcnt / zl) : 0.f;   // = deg / Z

        float scr[4];
        #pragma unroll
        for (int rg = 0; rg < 4; rg++) scr[rg] = __shfl(sc, 4 * hh + rg);

        // C layout: col = rlo, row(within frag) = 4*hh + rg
        float* ob = out + ((size_t)(b * NN + n0 + wid4 * 16)) * DD + rlo;
        #pragma unroll
        for (int j = 0; j < 8; j++)
            #pragma unroll
            for (int rg = 0; rg < 4; rg++)
                ob[(size_t)(4 * hh + rg) * DD + j * 16] = acc[j][rg] * scr[rg];
    }
}

extern "C" void kernel_launch(void* const* d_in, const int* in_sizes, int n_in,
                              void* d_out, int out_size, void* d_ws, size_t ws_size,
                              hipStream_t stream) {
    const float* h   = (const float*)d_in[0];
    const float* g   = (const float*)d_in[1];
    const int*   adj = (const int*)d_in[2];
    const float* a1  = (const float*)d_in[3];
    const float* a2  = (const float*)d_in[4];
    float* out = (float*)d_out;

    // workspace: e1 @0 (128 KB), e2B @128K (128 KB), e2D @256K (128 KB),
    //            gq @512K (8 MB)
    char* ws = (char*)d_ws;
    float*    e1  = (float*)(ws);
    float*    e2B = (float*)(ws + (128u << 10));
    float*    e2D = (float*)(ws + (256u << 10));
    ushort_t* gq  = (ushort_t*)(ws + (512u << 10));

    prep<<<dim3(MM / 64, BB), 256, 0, stream>>>(g, h, a1, a2, gq, e1, e2B, e2D);
    attn_tiled<<<dim3(NN / 64, BB), 512, 0, stream>>>(adj, gq, e1, e2B, e2D, out);
}